// Round 3
// baseline (923.609 us; speedup 1.0000x reference)
//
#include <hip/hip_runtime.h>

// R-GCN layer: out[v] = sum_{e: dst[e]=v} norm[e] * (h[src[e]] @ W[rel[e]])
//
// v4: coarse-bucket restructure. Exact per-dst sort (which caused 8x write
// amplification + 1.6M returning atomics in k_scatter) is replaced by 391
// coarse buckets of 128 dst nodes. k_out2 accumulates a [128][64] f32 tile in
// LDS via ds_add_f32, so edges only need coarse binning:
//   k_hist2   coarse histogram (LDS-aggregated)
//   k_scanc   scan of 391 bucket counts (1 block)
//   k_scatter2 per-block LDS counting sort of 8192 edges -> burst writes
//   k_pre     T[n,r,:] = bf16(h[n] @ W[r])   (unchanged)
//   k_out2    per-bucket LDS accumulate + plain coalesced store

#define N_NODES 50000
#define N_EDGES 1600000
#define D 64
#define N_REL 32

#define BSHIFT 7                 // 128 nodes per coarse bucket
#define NPB 128
#define NB 391                   // ceil(50000/128)
#define EPB 8192                 // edges per scatter/hist block
#define SC_BLOCKS 196            // ceil(1.6M/8192)

#define PCHUNK 512
#define PRE_BLOCKS_X 98          // ceil(50000/512)

typedef __attribute__((ext_vector_type(8))) __bf16 bf16x8;
typedef __attribute__((ext_vector_type(4))) __bf16 bf16x4;
typedef __attribute__((ext_vector_type(4))) float f32x4;

// ws layout (bytes):
//   [0x0000, 0x1000)      gcnt[NB] ints
//   [0x1000, 0x2000)      base[NB+1] ints
//   [0x2000, 0x3000)      cursor[NB] ints
//   [0x100000, 0xD40000)  payload int2[1.6M] (12.8 MB)
//   [0xE00000, ...)       T bf16 [N_NODES][rpg][64]  (204.8 MB / G)

__global__ __launch_bounds__(512) void k_zeroc(int* __restrict__ gcnt) {
    if (threadIdx.x < NB) gcnt[threadIdx.x] = 0;
}

__global__ __launch_bounds__(256) void k_hist2(const int* __restrict__ dst,
                                               int* __restrict__ gcnt) {
    __shared__ int lc[NB];
    for (int b = threadIdx.x; b < NB; b += 256) lc[b] = 0;
    __syncthreads();
    const int e0 = blockIdx.x * EPB;
    #pragma unroll
    for (int j = 0; j < 32; ++j) {
        int e = e0 + j * 256 + threadIdx.x;
        if (e < N_EDGES) atomicAdd(&lc[dst[e] >> BSHIFT], 1);
    }
    __syncthreads();
    for (int b = threadIdx.x; b < NB; b += 256)
        if (lc[b]) atomicAdd(&gcnt[b], lc[b]);
}

// Exclusive scan of gcnt[0..NB) -> base[0..NB], base[NB]=total; cursor=base.
__global__ __launch_bounds__(512) void k_scanc(const int* __restrict__ gcnt,
                                               int* __restrict__ base,
                                               int* __restrict__ cur) {
    const int t = threadIdx.x;
    const int lane = t & 63;
    const int w = t >> 6;
    int v = (t < NB) ? gcnt[t] : 0;
    int x = v;
    #pragma unroll
    for (int d = 1; d < 64; d <<= 1) {
        int n = __shfl_up(x, d, 64);
        if (lane >= d) x += n;
    }
    __shared__ int wt[8];
    if (lane == 63) wt[w] = x;
    __syncthreads();
    if (t == 0) {
        int run = 0;
        #pragma unroll
        for (int i = 0; i < 8; ++i) { int tmp = wt[i]; wt[i] = run; run += tmp; }
    }
    __syncthreads();
    int excl = x - v + wt[w];
    if (t < NB) { base[t] = excl; cur[t] = excl; }
    if (t == NB - 1) base[NB] = excl + v;
}

// Per-block LDS counting sort of 8192 edges into NB coarse buckets, then
// burst-write contiguous per-bucket runs to globally reserved ranges.
// payload: x = (dstLocal<<21) | (src*32 + rel)   (21-bit key, 7-bit dl)
//          y = bits(norm)
__global__ __launch_bounds__(256) void k_scatter2(
        const int* __restrict__ src, const int* __restrict__ dst,
        const int* __restrict__ rel, const float* __restrict__ norm,
        int* __restrict__ cur, int2* __restrict__ pay) {
    __shared__ int cnt[NB];
    __shared__ int bl[NB + 1];
    __shared__ int gb[NB];
    __shared__ unsigned short bid[EPB];
    __shared__ int2 stage[EPB];
    __shared__ int wt[8];

    const int t = threadIdx.x;
    const int lane = t & 63;
    const int w = t >> 6;
    const int e0 = blockIdx.x * EPB;

    for (int b = t; b < NB; b += 256) cnt[b] = 0;
    __syncthreads();

    // pass 1: count
    #pragma unroll
    for (int j = 0; j < 32; ++j) {
        int e = e0 + j * 256 + t;
        if (e < N_EDGES) atomicAdd(&cnt[dst[e] >> BSHIFT], 1);
    }
    __syncthreads();

    // exclusive scan of cnt[0..NB) with 256 threads handling 2 elems each
    {
        int x0 = (t < NB) ? cnt[t] : 0;
        int x1 = (t + 256 < NB) ? cnt[t + 256] : 0;
        int s0 = x0, s1 = x1;
        #pragma unroll
        for (int d = 1; d < 64; d <<= 1) {
            int n0 = __shfl_up(s0, d, 64);
            int n1 = __shfl_up(s1, d, 64);
            if (lane >= d) { s0 += n0; s1 += n1; }
        }
        if (lane == 63) { wt[w] = s0; wt[4 + w] = s1; }
        __syncthreads();
        if (t == 0) {
            int run = 0;
            #pragma unroll
            for (int i = 0; i < 8; ++i) { int tmp = wt[i]; wt[i] = run; run += tmp; }
        }
        __syncthreads();
        int ex0 = s0 - x0 + wt[w];
        int ex1 = s1 - x1 + wt[4 + w];
        if (t < NB) bl[t] = ex0;
        if (t + 256 < NB) bl[t + 256] = ex1;
        if (t == 0) {
            int tot = e0 + EPB <= N_EDGES ? EPB : (N_EDGES > e0 ? N_EDGES - e0 : 0);
            bl[NB] = tot;
        }
    }
    __syncthreads();

    // reserve global ranges (one atomic per non-empty bucket per block)
    for (int b = t; b < NB; b += 256) {
        int c = bl[b + 1] - bl[b];
        gb[b] = c ? atomicAdd(&cur[b], c) : 0;
    }
    // reset cnt for ranking
    for (int b = t; b < NB; b += 256) cnt[b] = 0;
    __syncthreads();

    // pass 2: stage into LDS in bucket-grouped order
    #pragma unroll
    for (int j = 0; j < 32; ++j) {
        int e = e0 + j * 256 + t;
        if (e < N_EDGES) {
            int dv = dst[e];
            int b = dv >> BSHIFT;
            int r = atomicAdd(&cnt[b], 1);
            int pos = bl[b] + r;
            stage[pos] = make_int2(((dv & (NPB - 1)) << 21) | (src[e] * N_REL + rel[e]),
                                   __float_as_int(norm[e]));
            bid[pos] = (unsigned short)b;
        }
    }
    __syncthreads();

    // pass 3: burst write to global reserved ranges (coalesced runs)
    const int total = bl[NB];
    for (int p = t; p < total; p += 256) {
        int b = bid[p];
        pay[gb[b] + (p - bl[b])] = stage[p];
    }
}

// T[n][rl][:] = h[n] @ W[r0+rl], bf16.  Swapped-operand MFMA: mfma(Wfrag, hfrag)
// puts 4 CONSECUTIVE out-dims per C fragment in each lane -> packed 8B stores.
__global__ __launch_bounds__(256) void k_pre(
        const float* __restrict__ h, const float* __restrict__ W,
        __bf16* __restrict__ T, int r0, int rpg) {
    const int rl = blockIdx.y;
    const int r = r0 + rl;
    const int chunk0 = blockIdx.x * PCHUNK;
    const int lane = threadIdx.x & 63;
    const int w = threadIdx.x >> 6;
    const int m = lane & 15;
    const int q = lane >> 4;

    const float* Wr = W + (size_t)r * D * D;
    bf16x8 Wf[2][4];
    #pragma unroll
    for (int kt = 0; kt < 2; ++kt) {
        #pragma unroll
        for (int ot = 0; ot < 4; ++ot) {
            bf16x8 b;
            #pragma unroll
            for (int j = 0; j < 8; ++j)
                b[j] = (__bf16)Wr[(kt * 32 + q * 8 + j) * D + ot * 16 + m];
            Wf[kt][ot] = b;
        }
    }

    const int end = min(chunk0 + PCHUNK, N_NODES);
    const f32x4 vzero = {0.f, 0.f, 0.f, 0.f};
    for (int n0 = chunk0; n0 < end; n0 += 64) {
        int node = n0 + w * 16 + m;
        const float* hrow = h + (size_t)min(node, N_NODES - 1) * D;
        f32x4 acc[4];
        #pragma unroll
        for (int ot = 0; ot < 4; ++ot) acc[ot] = vzero;
        #pragma unroll
        for (int kt = 0; kt < 2; ++kt) {
            const float4* ap = (const float4*)(hrow + kt * 32 + q * 8);
            float4 a0 = ap[0];
            float4 a1 = ap[1];
            bf16x8 a;
            a[0] = (__bf16)a0.x; a[1] = (__bf16)a0.y; a[2] = (__bf16)a0.z; a[3] = (__bf16)a0.w;
            a[4] = (__bf16)a1.x; a[5] = (__bf16)a1.y; a[6] = (__bf16)a1.z; a[7] = (__bf16)a1.w;
            #pragma unroll
            for (int ot = 0; ot < 4; ++ot)
                acc[ot] = __builtin_amdgcn_mfma_f32_16x16x32_bf16(Wf[kt][ot], a, acc[ot], 0, 0, 0);
        }
        if (node < N_NODES) {
            __bf16* trow = T + ((size_t)node * rpg + rl) * D;
            #pragma unroll
            for (int ot = 0; ot < 4; ++ot) {
                bf16x4 o;
                o[0] = (__bf16)acc[ot][0];
                o[1] = (__bf16)acc[ot][1];
                o[2] = (__bf16)acc[ot][2];
                o[3] = (__bf16)acc[ot][3];
                *(bf16x4*)(trow + ot * 16 + q * 4) = o;
            }
        }
    }
}

// One block per coarse bucket (128 dst nodes). 8 waves; lane = out dim.
// Per edge: broadcast 8B payload + coalesced 128B T-row gather + ds_add_f32
// into the LDS [128][64] f32 tile. Epilogue: plain coalesced store.
__global__ __launch_bounds__(512) void k_out2(
        const unsigned short* __restrict__ T, const int* __restrict__ base,
        const int2* __restrict__ pay, float* __restrict__ out,
        int r0, int r1, int rpg, int first) {
    __shared__ float acc[NPB * D];   // 32 KB
    const int t = threadIdx.x;
    const int lane = t & 63;
    const int w = t >> 6;
    const int b = blockIdx.x;

    #pragma unroll
    for (int j = 0; j < 4; ++j)
        ((float4*)acc)[j * 512 + t] = make_float4(0.f, 0.f, 0.f, 0.f);
    __syncthreads();

    const int s = base[b];
    const int e = base[b + 1];

    if (rpg == N_REL) {
        int i = s + w;
        for (; i + 24 < e; i += 32) {
            int2 p0 = pay[i];
            int2 p1 = pay[i + 8];
            int2 p2 = pay[i + 16];
            int2 p3 = pay[i + 24];
            float t0 = __uint_as_float(((unsigned int)T[((size_t)(p0.x & 0x1FFFFF) << 6) + lane]) << 16);
            float t1 = __uint_as_float(((unsigned int)T[((size_t)(p1.x & 0x1FFFFF) << 6) + lane]) << 16);
            float t2 = __uint_as_float(((unsigned int)T[((size_t)(p2.x & 0x1FFFFF) << 6) + lane]) << 16);
            float t3 = __uint_as_float(((unsigned int)T[((size_t)(p3.x & 0x1FFFFF) << 6) + lane]) << 16);
            atomicAdd(&acc[((p0.x >> 21) << 6) + lane], t0 * __int_as_float(p0.y));
            atomicAdd(&acc[((p1.x >> 21) << 6) + lane], t1 * __int_as_float(p1.y));
            atomicAdd(&acc[((p2.x >> 21) << 6) + lane], t2 * __int_as_float(p2.y));
            atomicAdd(&acc[((p3.x >> 21) << 6) + lane], t3 * __int_as_float(p3.y));
        }
        for (; i < e; i += 8) {
            int2 p = pay[i];
            float tv = __uint_as_float(((unsigned int)T[((size_t)(p.x & 0x1FFFFF) << 6) + lane]) << 16);
            atomicAdd(&acc[((p.x >> 21) << 6) + lane], tv * __int_as_float(p.y));
        }
    } else {
        // grouped fallback (small workspace): only rels in [r0, r1)
        for (int i = s + w; i < e; i += 8) {
            int2 p = pay[i];
            int key = p.x & 0x1FFFFF;
            int rlv = key & (N_REL - 1);
            if (rlv >= r0 && rlv < r1) {
                size_t row = (size_t)(key >> 5) * rpg + (rlv - r0);
                float tv = __uint_as_float(((unsigned int)T[(row << 6) + lane]) << 16);
                atomicAdd(&acc[((p.x >> 21) << 6) + lane], tv * __int_as_float(p.y));
            }
        }
    }
    __syncthreads();

    const int node0 = b * NPB;
    const int nrows = min(NPB, N_NODES - node0);
    const int nf4 = nrows * 16;      // float4s to write
    float4* op = (float4*)out + (size_t)node0 * 16;
    for (int idx = t; idx < nf4; idx += 512) {
        float4 v = ((float4*)acc)[idx];
        if (!first) {
            float4 pv = op[idx];
            v.x += pv.x; v.y += pv.y; v.z += pv.z; v.w += pv.w;
        }
        op[idx] = v;
    }
}

extern "C" void kernel_launch(void* const* d_in, const int* in_sizes, int n_in,
                              void* d_out, int out_size, void* d_ws, size_t ws_size,
                              hipStream_t stream) {
    const float* h    = (const float*)d_in[0];
    const float* W    = (const float*)d_in[1];
    const int*   src  = (const int*)d_in[2];
    const int*   dst  = (const int*)d_in[3];
    const int*   rel  = (const int*)d_in[4];
    const float* norm = (const float*)d_in[5];
    float* out = (float*)d_out;

    char* ws = (char*)d_ws;
    int*    gcnt = (int*)(ws);
    int*    base = (int*)(ws + 0x1000);
    int*    cur  = (int*)(ws + 0x2000);
    int2*   pay  = (int2*)(ws + 0x100000);
    __bf16* T    = (__bf16*)(ws + 0xE00000);

    // Pick the largest rel-group size whose T fits the workspace (expect G=1).
    const size_t tbytes_full = (size_t)N_NODES * N_REL * D * sizeof(__bf16); // 204.8 MB
    int G = 1;
    while (G < N_REL) {
        if ((size_t)0xE00000 + tbytes_full / G <= ws_size) break;
        G <<= 1;
    }
    const int rpg = N_REL / G;

    k_zeroc<<<1, 512, 0, stream>>>(gcnt);
    k_hist2<<<SC_BLOCKS, 256, 0, stream>>>(dst, gcnt);
    k_scanc<<<1, 512, 0, stream>>>(gcnt, base, cur);
    k_scatter2<<<SC_BLOCKS, 256, 0, stream>>>(src, dst, rel, norm, cur, pay);

    for (int g = 0; g < G; ++g) {
        k_pre<<<dim3(PRE_BLOCKS_X, rpg), 256, 0, stream>>>(h, W, T, g * rpg, rpg);
        k_out2<<<NB, 512, 0, stream>>>((const unsigned short*)T, base, pay, out,
                                       g * rpg, (g + 1) * rpg, rpg, g == 0);
    }
}

// Round 5
// 314.148 us; speedup vs baseline: 2.9400x; 2.9400x over previous
//
#include <hip/hip_runtime.h>

// R-GCN layer: out[v] = sum_{e: dst[e]=v} norm[e] * (h[src[e]] @ W[rel[e]])
//
// v5b: identical structure to v5 (bench-infra failure last round, no counter
// evidence against it); k_sort hardened: SORT_CAP 6144->8192 (+clamp) so the
// only theoretically-possible LDS-OOB path (bucket > cap) cannot fault.
//   k_hist2    coarse histogram (LDS-aggregated, 391 buckets of 128 nodes)
//   k_scanc    scan of 391 bucket counts (1 block)
//   k_scatter2 per-block LDS counting sort of 8192 edges -> burst writes
//   k_sort     per-bucket exact sort by dst (in-place, LDS-staged) + offs[]
//   k_pre      T[n,r,:] = bf16(h[n] @ W[r])
//   k_out      one wave per dst node, 4-wide unrolled gather-FMA, plain store

#define N_NODES 50000
#define N_EDGES 1600000
#define D 64
#define N_REL 32

#define BSHIFT 7                 // 128 nodes per coarse bucket
#define NPB 128
#define NB 391                   // ceil(50000/128)
#define EPB 8192                 // edges per scatter/hist block
#define SC_BLOCKS 196            // ceil(1.6M/8192)
#define SORT_CAP 8192            // bucket capacity (mean 4096, sd 64 -> +64sd)

#define PCHUNK 512
#define PRE_BLOCKS_X 98          // ceil(50000/512)

typedef __attribute__((ext_vector_type(8))) __bf16 bf16x8;
typedef __attribute__((ext_vector_type(4))) __bf16 bf16x4;
typedef __attribute__((ext_vector_type(4))) float f32x4;

// ws layout (bytes):
//   [0x0000, 0x1000)      gcnt[NB] ints
//   [0x1000, 0x2000)      base[NB+1] ints
//   [0x2000, 0x3000)      cursor[NB] ints
//   [0x3000, 0x35000)     offs[50001] ints
//   [0x100000, 0xD40000)  payload int2[1.6M] (12.8 MB)
//   [0xE00000, ...)       T bf16 [N_NODES][rpg][64]  (204.8 MB / G)

__global__ __launch_bounds__(512) void k_zeroc(int* __restrict__ gcnt) {
    if (threadIdx.x < NB) gcnt[threadIdx.x] = 0;
}

__global__ __launch_bounds__(256) void k_hist2(const int* __restrict__ dst,
                                               int* __restrict__ gcnt) {
    __shared__ int lc[NB];
    for (int b = threadIdx.x; b < NB; b += 256) lc[b] = 0;
    __syncthreads();
    const int e0 = blockIdx.x * EPB;
    #pragma unroll
    for (int j = 0; j < 32; ++j) {
        int e = e0 + j * 256 + threadIdx.x;
        if (e < N_EDGES) atomicAdd(&lc[dst[e] >> BSHIFT], 1);
    }
    __syncthreads();
    for (int b = threadIdx.x; b < NB; b += 256)
        if (lc[b]) atomicAdd(&gcnt[b], lc[b]);
}

// Exclusive scan of gcnt[0..NB) -> base[0..NB], base[NB]=total; cursor=base.
__global__ __launch_bounds__(512) void k_scanc(const int* __restrict__ gcnt,
                                               int* __restrict__ base,
                                               int* __restrict__ cur) {
    const int t = threadIdx.x;
    const int lane = t & 63;
    const int w = t >> 6;
    int v = (t < NB) ? gcnt[t] : 0;
    int x = v;
    #pragma unroll
    for (int d = 1; d < 64; d <<= 1) {
        int n = __shfl_up(x, d, 64);
        if (lane >= d) x += n;
    }
    __shared__ int wt[8];
    if (lane == 63) wt[w] = x;
    __syncthreads();
    if (t == 0) {
        int run = 0;
        #pragma unroll
        for (int i = 0; i < 8; ++i) { int tmp = wt[i]; wt[i] = run; run += tmp; }
    }
    __syncthreads();
    int excl = x - v + wt[w];
    if (t < NB) { base[t] = excl; cur[t] = excl; }
    if (t == NB - 1) base[NB] = excl + v;
}

// Per-block LDS counting sort of 8192 edges into NB coarse buckets, then
// burst-write contiguous per-bucket runs to globally reserved ranges.
// payload: x = (dstLocal<<21) | (src*32 + rel)   (21-bit key, 7-bit dl)
//          y = bits(norm)
__global__ __launch_bounds__(256) void k_scatter2(
        const int* __restrict__ src, const int* __restrict__ dst,
        const int* __restrict__ rel, const float* __restrict__ norm,
        int* __restrict__ cur, int2* __restrict__ pay) {
    __shared__ int cnt[NB];
    __shared__ int bl[NB + 1];
    __shared__ int gb[NB];
    __shared__ unsigned short bid[EPB];
    __shared__ int2 stage[EPB];
    __shared__ int wt[8];

    const int t = threadIdx.x;
    const int lane = t & 63;
    const int w = t >> 6;
    const int e0 = blockIdx.x * EPB;

    for (int b = t; b < NB; b += 256) cnt[b] = 0;
    __syncthreads();

    // pass 1: count
    #pragma unroll
    for (int j = 0; j < 32; ++j) {
        int e = e0 + j * 256 + t;
        if (e < N_EDGES) atomicAdd(&cnt[dst[e] >> BSHIFT], 1);
    }
    __syncthreads();

    // exclusive scan of cnt[0..NB)
    {
        int x0 = (t < NB) ? cnt[t] : 0;
        int x1 = (t + 256 < NB) ? cnt[t + 256] : 0;
        int s0 = x0, s1 = x1;
        #pragma unroll
        for (int d = 1; d < 64; d <<= 1) {
            int n0 = __shfl_up(s0, d, 64);
            int n1 = __shfl_up(s1, d, 64);
            if (lane >= d) { s0 += n0; s1 += n1; }
        }
        if (lane == 63) { wt[w] = s0; wt[4 + w] = s1; }
        __syncthreads();
        if (t == 0) {
            int run = 0;
            #pragma unroll
            for (int i = 0; i < 8; ++i) { int tmp = wt[i]; wt[i] = run; run += tmp; }
        }
        __syncthreads();
        int ex0 = s0 - x0 + wt[w];
        int ex1 = s1 - x1 + wt[4 + w];
        if (t < NB) bl[t] = ex0;
        if (t + 256 < NB) bl[t + 256] = ex1;
        if (t == 0) {
            int tot = e0 + EPB <= N_EDGES ? EPB : (N_EDGES > e0 ? N_EDGES - e0 : 0);
            bl[NB] = tot;
        }
    }
    __syncthreads();

    // reserve global ranges (one atomic per non-empty bucket per block)
    for (int b = t; b < NB; b += 256) {
        int c = bl[b + 1] - bl[b];
        gb[b] = c ? atomicAdd(&cur[b], c) : 0;
    }
    for (int b = t; b < NB; b += 256) cnt[b] = 0;
    __syncthreads();

    // pass 2: stage into LDS in bucket-grouped order
    #pragma unroll
    for (int j = 0; j < 32; ++j) {
        int e = e0 + j * 256 + t;
        if (e < N_EDGES) {
            int dv = dst[e];
            int b = dv >> BSHIFT;
            int r = atomicAdd(&cnt[b], 1);
            int pos = bl[b] + r;
            stage[pos] = make_int2(((dv & (NPB - 1)) << 21) | (src[e] * N_REL + rel[e]),
                                   __float_as_int(norm[e]));
            bid[pos] = (unsigned short)b;
        }
    }
    __syncthreads();

    // pass 3: burst write to global reserved ranges (coalesced runs)
    const int total = bl[NB];
    for (int p = t; p < total; p += 256) {
        int b = bid[p];
        pay[gb[b] + (p - bl[b])] = stage[p];
    }
}

// One block per coarse bucket: stage the bucket's edges in LDS, counting-sort
// by exact local dst, write back IN PLACE in sorted order, and emit per-node
// global offsets (bucket base + local exclusive scan).
__global__ __launch_bounds__(512) void k_sort(
        const int* __restrict__ base, int2* __restrict__ pay,
        int* __restrict__ offs) {
    __shared__ int2 stage[SORT_CAP];   // 64 KB
    __shared__ int cnt[NPB];
    __shared__ int curl[NPB];
    __shared__ int wsum[2];

    const int t = threadIdx.x;
    const int lane = t & 63;
    const int b = blockIdx.x;
    const int s = base[b];
    const int e = base[b + 1];
    const int n = min(e - s, SORT_CAP);   // clamp: cap overflow degrades, never faults

    if (t < NPB) cnt[t] = 0;
    __syncthreads();

    // stage + count
    for (int j = t; j < n; j += 512) {
        int2 p = pay[s + j];
        stage[j] = p;
        atomicAdd(&cnt[p.x >> 21], 1);
    }
    __syncthreads();

    // exclusive scan of cnt[0..128) with 2 waves
    int vcnt = 0, x = 0;
    if (t < NPB) {
        vcnt = cnt[t];
        x = vcnt;
        #pragma unroll
        for (int d = 1; d < 64; d <<= 1) {
            int nn = __shfl_up(x, d, 64);
            if (lane >= d) x += nn;
        }
        if (lane == 63) wsum[t >> 6] = x;
    }
    __syncthreads();
    if (t < NPB) {
        int excl = x - vcnt + ((t >= 64) ? wsum[0] : 0);
        curl[t] = excl;
        int node = b * NPB + t;
        if (node < N_NODES) offs[node] = s + excl;
    }
    if (b == NB - 1 && t == 0) offs[N_NODES] = e;
    __syncthreads();

    // scatter back in place, sorted by local dst
    for (int j = t; j < n; j += 512) {
        int2 p = stage[j];
        int pos = atomicAdd(&curl[p.x >> 21], 1);
        pay[s + pos] = p;
    }
}

// T[n][rl][:] = h[n] @ W[r0+rl], bf16.  Swapped-operand MFMA: mfma(Wfrag, hfrag)
// puts 4 CONSECUTIVE out-dims per C fragment in each lane -> packed 8B stores.
__global__ __launch_bounds__(256) void k_pre(
        const float* __restrict__ h, const float* __restrict__ W,
        __bf16* __restrict__ T, int r0, int rpg) {
    const int rl = blockIdx.y;
    const int r = r0 + rl;
    const int chunk0 = blockIdx.x * PCHUNK;
    const int lane = threadIdx.x & 63;
    const int w = threadIdx.x >> 6;
    const int m = lane & 15;
    const int q = lane >> 4;

    const float* Wr = W + (size_t)r * D * D;
    bf16x8 Wf[2][4];
    #pragma unroll
    for (int kt = 0; kt < 2; ++kt) {
        #pragma unroll
        for (int ot = 0; ot < 4; ++ot) {
            bf16x8 bfr;
            #pragma unroll
            for (int j = 0; j < 8; ++j)
                bfr[j] = (__bf16)Wr[(kt * 32 + q * 8 + j) * D + ot * 16 + m];
            Wf[kt][ot] = bfr;
        }
    }

    const int end = min(chunk0 + PCHUNK, N_NODES);
    const f32x4 vzero = {0.f, 0.f, 0.f, 0.f};
    for (int n0 = chunk0; n0 < end; n0 += 64) {
        int node = n0 + w * 16 + m;
        const float* hrow = h + (size_t)min(node, N_NODES - 1) * D;
        f32x4 acc[4];
        #pragma unroll
        for (int ot = 0; ot < 4; ++ot) acc[ot] = vzero;
        #pragma unroll
        for (int kt = 0; kt < 2; ++kt) {
            const float4* ap = (const float4*)(hrow + kt * 32 + q * 8);
            float4 a0 = ap[0];
            float4 a1 = ap[1];
            bf16x8 a;
            a[0] = (__bf16)a0.x; a[1] = (__bf16)a0.y; a[2] = (__bf16)a0.z; a[3] = (__bf16)a0.w;
            a[4] = (__bf16)a1.x; a[5] = (__bf16)a1.y; a[6] = (__bf16)a1.z; a[7] = (__bf16)a1.w;
            #pragma unroll
            for (int ot = 0; ot < 4; ++ot)
                acc[ot] = __builtin_amdgcn_mfma_f32_16x16x32_bf16(Wf[kt][ot], a, acc[ot], 0, 0, 0);
        }
        if (node < N_NODES) {
            __bf16* trow = T + ((size_t)node * rpg + rl) * D;
            #pragma unroll
            for (int ot = 0; ot < 4; ++ot) {
                bf16x4 o;
                o[0] = (__bf16)acc[ot][0];
                o[1] = (__bf16)acc[ot][1];
                o[2] = (__bf16)acc[ot][2];
                o[3] = (__bf16)acc[ot][3];
                *(bf16x4*)(trow + ot * 16 + q * 4) = o;
            }
        }
    }
}

// One wave per dst node; lane = out dim. Per edge: uniform 8B payload load +
// one coalesced 128B line gather from T + FMA. Plain store, no atomics.
// 4-wide unroll: 4 independent gathers in flight per wave.
__global__ __launch_bounds__(256) void k_out(
        const unsigned short* __restrict__ T, const int* __restrict__ offs,
        const int2* __restrict__ pay, float* __restrict__ out,
        int r0, int r1, int rpg, int first) {
    const int v = (blockIdx.x << 2) + (threadIdx.x >> 6);
    const int lane = threadIdx.x & 63;
    const int s = offs[v];
    const int e = offs[v + 1];
    const size_t orow = ((size_t)v << 6) + lane;

    float acc0 = first ? 0.f : out[orow];
    float acc1 = 0.f, acc2 = 0.f, acc3 = 0.f;
    int i = s;
    if (rpg == N_REL) {
        for (; i + 4 <= e; i += 4) {
            int2 p0 = pay[i];
            int2 p1 = pay[i + 1];
            int2 p2 = pay[i + 2];
            int2 p3 = pay[i + 3];
            float t0 = __uint_as_float(((unsigned int)T[((size_t)(p0.x & 0x1FFFFF) << 6) + lane]) << 16);
            float t1 = __uint_as_float(((unsigned int)T[((size_t)(p1.x & 0x1FFFFF) << 6) + lane]) << 16);
            float t2 = __uint_as_float(((unsigned int)T[((size_t)(p2.x & 0x1FFFFF) << 6) + lane]) << 16);
            float t3 = __uint_as_float(((unsigned int)T[((size_t)(p3.x & 0x1FFFFF) << 6) + lane]) << 16);
            acc0 = fmaf(__int_as_float(p0.y), t0, acc0);
            acc1 = fmaf(__int_as_float(p1.y), t1, acc1);
            acc2 = fmaf(__int_as_float(p2.y), t2, acc2);
            acc3 = fmaf(__int_as_float(p3.y), t3, acc3);
        }
        for (; i < e; ++i) {
            int2 p = pay[i];
            float tv = __uint_as_float(((unsigned int)T[((size_t)(p.x & 0x1FFFFF) << 6) + lane]) << 16);
            acc0 = fmaf(__int_as_float(p.y), tv, acc0);
        }
    } else {
        // grouped fallback (small workspace): only rels in [r0, r1)
        for (; i < e; ++i) {
            int2 p = pay[i];
            int key = p.x & 0x1FFFFF;
            int rlv = key & (N_REL - 1);
            if (rlv >= r0 && rlv < r1) {
                size_t row = (size_t)(key >> 5) * rpg + (rlv - r0);
                float tv = __uint_as_float(((unsigned int)T[(row << 6) + lane]) << 16);
                acc0 = fmaf(__int_as_float(p.y), tv, acc0);
            }
        }
    }
    out[orow] = (acc0 + acc1) + (acc2 + acc3);
}

extern "C" void kernel_launch(void* const* d_in, const int* in_sizes, int n_in,
                              void* d_out, int out_size, void* d_ws, size_t ws_size,
                              hipStream_t stream) {
    const float* h    = (const float*)d_in[0];
    const float* W    = (const float*)d_in[1];
    const int*   src  = (const int*)d_in[2];
    const int*   dst  = (const int*)d_in[3];
    const int*   rel  = (const int*)d_in[4];
    const float* norm = (const float*)d_in[5];
    float* out = (float*)d_out;

    char* ws = (char*)d_ws;
    int*    gcnt = (int*)(ws);
    int*    base = (int*)(ws + 0x1000);
    int*    cur  = (int*)(ws + 0x2000);
    int*    offs = (int*)(ws + 0x3000);
    int2*   pay  = (int2*)(ws + 0x100000);
    __bf16* T    = (__bf16*)(ws + 0xE00000);

    // Pick the largest rel-group size whose T fits the workspace (expect G=1).
    const size_t tbytes_full = (size_t)N_NODES * N_REL * D * sizeof(__bf16); // 204.8 MB
    int G = 1;
    while (G < N_REL) {
        if ((size_t)0xE00000 + tbytes_full / G <= ws_size) break;
        G <<= 1;
    }
    const int rpg = N_REL / G;

    k_zeroc<<<1, 512, 0, stream>>>(gcnt);
    k_hist2<<<SC_BLOCKS, 256, 0, stream>>>(dst, gcnt);
    k_scanc<<<1, 512, 0, stream>>>(gcnt, base, cur);
    k_scatter2<<<SC_BLOCKS, 256, 0, stream>>>(src, dst, rel, norm, cur, pay);
    k_sort<<<NB, 512, 0, stream>>>(base, pay, offs);

    for (int g = 0; g < G; ++g) {
        k_pre<<<dim3(PRE_BLOCKS_X, rpg), 256, 0, stream>>>(h, W, T, g * rpg, rpg);
        k_out<<<N_NODES / 4, 256, 0, stream>>>((const unsigned short*)T, offs, pay, out,
                                               g * rpg, (g + 1) * rpg, rpg, g == 0);
    }
}

// Round 6
// 290.643 us; speedup vs baseline: 3.1778x; 1.0809x over previous
//
#include <hip/hip_runtime.h>

// R-GCN layer: out[v] = sum_{e: dst[e]=v} norm[e] * (h[src[e]] @ W[rel[e]])
//
// v6: v5 structure with k_pre restructured for h-reuse. Old k_pre fetched h
// once PER RELATION (32x redundancy -> 180MB HBM fetch). New k_pre: one block
// per 64-node chunk, h staged once in LDS (bf16, XOR-swizzled), loop over all
// 32 rels inside the block. W is pre-packed into per-lane MFMA fragment order
// by k_wconv (256KB, L2-resident) so per-rel W loads are 8 coalesced 16B
// loads instead of 64 strided scalar gathers.
//   k_hist2    coarse histogram (391 buckets of 128 nodes)
//   k_scanc    scan of 391 bucket counts
//   k_scatter2 per-block LDS counting sort of 8192 edges -> burst writes
//   k_sort     per-bucket exact sort by dst + offs[]
//   k_wconv    pack W -> per-lane bf16 MFMA fragments
//   k_pre      T[n,r,:] = bf16(h[n] @ W[r]), h staged once per chunk
//   k_out      one wave per dst node, 4-wide unrolled gather-FMA, plain store

#define N_NODES 50000
#define N_EDGES 1600000
#define D 64
#define N_REL 32

#define BSHIFT 7                 // 128 nodes per coarse bucket
#define NPB 128
#define NB 391                   // ceil(50000/128)
#define EPB 8192                 // edges per scatter/hist block
#define SC_BLOCKS 196            // ceil(1.6M/8192)
#define SORT_CAP 8192            // bucket capacity (mean 4096, sd 64)

#define PRE_CHUNK 64
#define PRE_BLOCKS 782           // ceil(50000/64)

typedef __attribute__((ext_vector_type(8))) __bf16 bf16x8;
typedef __attribute__((ext_vector_type(4))) __bf16 bf16x4;
typedef __attribute__((ext_vector_type(4))) float f32x4;

// ws layout (bytes):
//   [0x0000, 0x1000)      gcnt[NB] ints
//   [0x1000, 0x2000)      base[NB+1] ints
//   [0x2000, 0x3000)      cursor[NB] ints
//   [0x3000, 0x35000)     offs[50001] ints
//   [0x100000, 0xD40000)  payload int2[1.6M] (12.8 MB)
//   [0xD40000, 0xD80000)  Wfrag bf16 [32][2][4][64][8]  (256 KB)
//   [0xE00000, ...)       T bf16 [N_NODES][rpg][64]  (204.8 MB / G)

__global__ __launch_bounds__(512) void k_zeroc(int* __restrict__ gcnt) {
    if (threadIdx.x < NB) gcnt[threadIdx.x] = 0;
}

__global__ __launch_bounds__(256) void k_hist2(const int* __restrict__ dst,
                                               int* __restrict__ gcnt) {
    __shared__ int lc[NB];
    for (int b = threadIdx.x; b < NB; b += 256) lc[b] = 0;
    __syncthreads();
    const int e0 = blockIdx.x * EPB;
    #pragma unroll
    for (int j = 0; j < 32; ++j) {
        int e = e0 + j * 256 + threadIdx.x;
        if (e < N_EDGES) atomicAdd(&lc[dst[e] >> BSHIFT], 1);
    }
    __syncthreads();
    for (int b = threadIdx.x; b < NB; b += 256)
        if (lc[b]) atomicAdd(&gcnt[b], lc[b]);
}

// Exclusive scan of gcnt[0..NB) -> base[0..NB], base[NB]=total; cursor=base.
__global__ __launch_bounds__(512) void k_scanc(const int* __restrict__ gcnt,
                                               int* __restrict__ base,
                                               int* __restrict__ cur) {
    const int t = threadIdx.x;
    const int lane = t & 63;
    const int w = t >> 6;
    int v = (t < NB) ? gcnt[t] : 0;
    int x = v;
    #pragma unroll
    for (int d = 1; d < 64; d <<= 1) {
        int n = __shfl_up(x, d, 64);
        if (lane >= d) x += n;
    }
    __shared__ int wt[8];
    if (lane == 63) wt[w] = x;
    __syncthreads();
    if (t == 0) {
        int run = 0;
        #pragma unroll
        for (int i = 0; i < 8; ++i) { int tmp = wt[i]; wt[i] = run; run += tmp; }
    }
    __syncthreads();
    int excl = x - v + wt[w];
    if (t < NB) { base[t] = excl; cur[t] = excl; }
    if (t == NB - 1) base[NB] = excl + v;
}

// Per-block LDS counting sort of 8192 edges into NB coarse buckets, then
// burst-write contiguous per-bucket runs to globally reserved ranges.
// payload: x = (dstLocal<<21) | (src*32 + rel), y = bits(norm)
__global__ __launch_bounds__(256) void k_scatter2(
        const int* __restrict__ src, const int* __restrict__ dst,
        const int* __restrict__ rel, const float* __restrict__ norm,
        int* __restrict__ cur, int2* __restrict__ pay) {
    __shared__ int cnt[NB];
    __shared__ int bl[NB + 1];
    __shared__ int gb[NB];
    __shared__ unsigned short bid[EPB];
    __shared__ int2 stage[EPB];
    __shared__ int wt[8];

    const int t = threadIdx.x;
    const int lane = t & 63;
    const int w = t >> 6;
    const int e0 = blockIdx.x * EPB;

    for (int b = t; b < NB; b += 256) cnt[b] = 0;
    __syncthreads();

    // pass 1: count
    #pragma unroll
    for (int j = 0; j < 32; ++j) {
        int e = e0 + j * 256 + t;
        if (e < N_EDGES) atomicAdd(&cnt[dst[e] >> BSHIFT], 1);
    }
    __syncthreads();

    // exclusive scan of cnt[0..NB)
    {
        int x0 = (t < NB) ? cnt[t] : 0;
        int x1 = (t + 256 < NB) ? cnt[t + 256] : 0;
        int s0 = x0, s1 = x1;
        #pragma unroll
        for (int d = 1; d < 64; d <<= 1) {
            int n0 = __shfl_up(s0, d, 64);
            int n1 = __shfl_up(s1, d, 64);
            if (lane >= d) { s0 += n0; s1 += n1; }
        }
        if (lane == 63) { wt[w] = s0; wt[4 + w] = s1; }
        __syncthreads();
        if (t == 0) {
            int run = 0;
            #pragma unroll
            for (int i = 0; i < 8; ++i) { int tmp = wt[i]; wt[i] = run; run += tmp; }
        }
        __syncthreads();
        int ex0 = s0 - x0 + wt[w];
        int ex1 = s1 - x1 + wt[4 + w];
        if (t < NB) bl[t] = ex0;
        if (t + 256 < NB) bl[t + 256] = ex1;
        if (t == 0) {
            int tot = e0 + EPB <= N_EDGES ? EPB : (N_EDGES > e0 ? N_EDGES - e0 : 0);
            bl[NB] = tot;
        }
    }
    __syncthreads();

    // reserve global ranges (one atomic per non-empty bucket per block)
    for (int b = t; b < NB; b += 256) {
        int c = bl[b + 1] - bl[b];
        gb[b] = c ? atomicAdd(&cur[b], c) : 0;
    }
    for (int b = t; b < NB; b += 256) cnt[b] = 0;
    __syncthreads();

    // pass 2: stage into LDS in bucket-grouped order
    #pragma unroll
    for (int j = 0; j < 32; ++j) {
        int e = e0 + j * 256 + t;
        if (e < N_EDGES) {
            int dv = dst[e];
            int b = dv >> BSHIFT;
            int r = atomicAdd(&cnt[b], 1);
            int pos = bl[b] + r;
            stage[pos] = make_int2(((dv & (NPB - 1)) << 21) | (src[e] * N_REL + rel[e]),
                                   __float_as_int(norm[e]));
            bid[pos] = (unsigned short)b;
        }
    }
    __syncthreads();

    // pass 3: burst write to global reserved ranges (coalesced runs)
    const int total = bl[NB];
    for (int p = t; p < total; p += 256) {
        int b = bid[p];
        pay[gb[b] + (p - bl[b])] = stage[p];
    }
}

// One block per coarse bucket: stage the bucket's edges in LDS, counting-sort
// by exact local dst, write back IN PLACE in sorted order, and emit per-node
// global offsets (bucket base + local exclusive scan).
__global__ __launch_bounds__(512) void k_sort(
        const int* __restrict__ base, int2* __restrict__ pay,
        int* __restrict__ offs) {
    __shared__ int2 stage[SORT_CAP];   // 64 KB
    __shared__ int cnt[NPB];
    __shared__ int curl[NPB];
    __shared__ int wsum[2];

    const int t = threadIdx.x;
    const int lane = t & 63;
    const int b = blockIdx.x;
    const int s = base[b];
    const int e = base[b + 1];
    const int n = min(e - s, SORT_CAP);   // clamp: overflow degrades, never faults

    if (t < NPB) cnt[t] = 0;
    __syncthreads();

    // stage + count
    for (int j = t; j < n; j += 512) {
        int2 p = pay[s + j];
        stage[j] = p;
        atomicAdd(&cnt[p.x >> 21], 1);
    }
    __syncthreads();

    // exclusive scan of cnt[0..128) with 2 waves
    int vcnt = 0, x = 0;
    if (t < NPB) {
        vcnt = cnt[t];
        x = vcnt;
        #pragma unroll
        for (int d = 1; d < 64; d <<= 1) {
            int nn = __shfl_up(x, d, 64);
            if (lane >= d) x += nn;
        }
        if (lane == 63) wsum[t >> 6] = x;
    }
    __syncthreads();
    if (t < NPB) {
        int excl = x - vcnt + ((t >= 64) ? wsum[0] : 0);
        curl[t] = excl;
        int node = b * NPB + t;
        if (node < N_NODES) offs[node] = s + excl;
    }
    if (b == NB - 1 && t == 0) offs[N_NODES] = e;
    __syncthreads();

    // scatter back in place, sorted by local dst
    for (int j = t; j < n; j += 512) {
        int2 p = stage[j];
        int pos = atomicAdd(&curl[p.x >> 21], 1);
        pay[s + pos] = p;
    }
}

// Pack W into per-lane MFMA A-fragment order:
// Wfrag[r][kt][ot][lane][j] = bf16( W[r][kt*32 + (lane>>4)*8 + j][ot*16 + (lane&15)] )
__global__ __launch_bounds__(256) void k_wconv(const float* __restrict__ W,
                                               __bf16* __restrict__ Wfrag) {
    const int r = blockIdx.x;
    const int lane = threadIdx.x & 63;
    const int jj = (threadIdx.x >> 6) * 2;   // 2 elems per thread per frag
    const int q = lane >> 4;
    const int m = lane & 15;
    const float* Wr = W + (size_t)r * D * D;
    #pragma unroll
    for (int kt = 0; kt < 2; ++kt) {
        #pragma unroll
        for (int ot = 0; ot < 4; ++ot) {
            size_t dbase = ((((size_t)r * 2 + kt) * 4 + ot) * 64 + lane) * 8 + jj;
            Wfrag[dbase]     = (__bf16)Wr[(kt * 32 + q * 8 + jj) * D + ot * 16 + m];
            Wfrag[dbase + 1] = (__bf16)Wr[(kt * 32 + q * 8 + jj + 1) * D + ot * 16 + m];
        }
    }
}

// T[n][rl][:] = h[n] @ W[r0+rl], bf16.  One block per 64-node chunk; h staged
// once in LDS (bf16, XOR-swizzled 16B chunks: chunk c stored at c^(row&7));
// waves loop over rels (wave-interleaved), reading W from packed Wfrag.
__global__ __launch_bounds__(256) void k_pre(
        const float* __restrict__ h, const __bf16* __restrict__ Wfrag,
        __bf16* __restrict__ T, int r0, int rpg) {
    __shared__ unsigned short hl[PRE_CHUNK * D];   // 8 KB
    const int t = threadIdx.x;
    const int lane = t & 63;
    const int w = t >> 6;
    const int m = lane & 15;
    const int q = lane >> 4;
    const int chunk0 = blockIdx.x * PRE_CHUNK;

    // stage h[chunk0 .. chunk0+64) as bf16, swizzled
    #pragma unroll
    for (int it = 0; it < 4; ++it) {
        int F = it * 256 + t;                  // float4 index over 64x64 floats
        int row = F >> 4;
        int gnode = min(chunk0 + row, N_NODES - 1);
        float4 v = ((const float4*)(h + (size_t)gnode * D))[F & 15];
        int c = (F & 15) >> 1;
        int off4 = (F & 1) * 4;
        bf16x4 o;
        o[0] = (__bf16)v.x; o[1] = (__bf16)v.y; o[2] = (__bf16)v.z; o[3] = (__bf16)v.w;
        *(bf16x4*)(hl + row * D + ((c ^ (row & 7)) << 3) + off4) = o;
    }
    __syncthreads();

    const f32x4 vzero = {0.f, 0.f, 0.f, 0.f};
    for (int rl = w; rl < rpg; rl += 4) {
        const int r = r0 + rl;
        // load packed W fragments: 8 coalesced 16B loads
        bf16x8 wf[2][4];
        #pragma unroll
        for (int kt = 0; kt < 2; ++kt)
            #pragma unroll
            for (int ot = 0; ot < 4; ++ot)
                wf[kt][ot] = *(const bf16x8*)(Wfrag + ((((size_t)r * 2 + kt) * 4 + ot) * 64 + lane) * 8);

        #pragma unroll
        for (int nt = 0; nt < 4; ++nt) {
            const int ln = nt * 16 + m;
            bf16x8 a0 = *(const bf16x8*)(hl + ln * D + (((0 * 4 + q) ^ (ln & 7)) << 3));
            bf16x8 a1 = *(const bf16x8*)(hl + ln * D + (((1 * 4 + q) ^ (ln & 7)) << 3));
            f32x4 acc[4];
            #pragma unroll
            for (int ot = 0; ot < 4; ++ot) acc[ot] = vzero;
            #pragma unroll
            for (int ot = 0; ot < 4; ++ot) {
                acc[ot] = __builtin_amdgcn_mfma_f32_16x16x32_bf16(wf[0][ot], a0, acc[ot], 0, 0, 0);
                acc[ot] = __builtin_amdgcn_mfma_f32_16x16x32_bf16(wf[1][ot], a1, acc[ot], 0, 0, 0);
            }
            const int node = chunk0 + ln;
            if (node < N_NODES) {
                __bf16* trow = T + ((size_t)node * rpg + rl) * D;
                #pragma unroll
                for (int ot = 0; ot < 4; ++ot) {
                    bf16x4 o;
                    o[0] = (__bf16)acc[ot][0];
                    o[1] = (__bf16)acc[ot][1];
                    o[2] = (__bf16)acc[ot][2];
                    o[3] = (__bf16)acc[ot][3];
                    *(bf16x4*)(trow + ot * 16 + q * 4) = o;
                }
            }
        }
    }
}

// One wave per dst node; lane = out dim. Per edge: uniform 8B payload load +
// one coalesced 128B line gather from T + FMA. Plain store, no atomics.
__global__ __launch_bounds__(256) void k_out(
        const unsigned short* __restrict__ T, const int* __restrict__ offs,
        const int2* __restrict__ pay, float* __restrict__ out,
        int r0, int r1, int rpg, int first) {
    const int v = (blockIdx.x << 2) + (threadIdx.x >> 6);
    const int lane = threadIdx.x & 63;
    const int s = offs[v];
    const int e = offs[v + 1];
    const size_t orow = ((size_t)v << 6) + lane;

    float acc0 = first ? 0.f : out[orow];
    float acc1 = 0.f, acc2 = 0.f, acc3 = 0.f;
    int i = s;
    if (rpg == N_REL) {
        for (; i + 4 <= e; i += 4) {
            int2 p0 = pay[i];
            int2 p1 = pay[i + 1];
            int2 p2 = pay[i + 2];
            int2 p3 = pay[i + 3];
            float t0 = __uint_as_float(((unsigned int)T[((size_t)(p0.x & 0x1FFFFF) << 6) + lane]) << 16);
            float t1 = __uint_as_float(((unsigned int)T[((size_t)(p1.x & 0x1FFFFF) << 6) + lane]) << 16);
            float t2 = __uint_as_float(((unsigned int)T[((size_t)(p2.x & 0x1FFFFF) << 6) + lane]) << 16);
            float t3 = __uint_as_float(((unsigned int)T[((size_t)(p3.x & 0x1FFFFF) << 6) + lane]) << 16);
            acc0 = fmaf(__int_as_float(p0.y), t0, acc0);
            acc1 = fmaf(__int_as_float(p1.y), t1, acc1);
            acc2 = fmaf(__int_as_float(p2.y), t2, acc2);
            acc3 = fmaf(__int_as_float(p3.y), t3, acc3);
        }
        for (; i < e; ++i) {
            int2 p = pay[i];
            float tv = __uint_as_float(((unsigned int)T[((size_t)(p.x & 0x1FFFFF) << 6) + lane]) << 16);
            acc0 = fmaf(__int_as_float(p.y), tv, acc0);
        }
    } else {
        // grouped fallback (small workspace): only rels in [r0, r1)
        for (; i < e; ++i) {
            int2 p = pay[i];
            int key = p.x & 0x1FFFFF;
            int rlv = key & (N_REL - 1);
            if (rlv >= r0 && rlv < r1) {
                size_t row = (size_t)(key >> 5) * rpg + (rlv - r0);
                float tv = __uint_as_float(((unsigned int)T[(row << 6) + lane]) << 16);
                acc0 = fmaf(__int_as_float(p.y), tv, acc0);
            }
        }
    }
    out[orow] = (acc0 + acc1) + (acc2 + acc3);
}

extern "C" void kernel_launch(void* const* d_in, const int* in_sizes, int n_in,
                              void* d_out, int out_size, void* d_ws, size_t ws_size,
                              hipStream_t stream) {
    const float* h    = (const float*)d_in[0];
    const float* W    = (const float*)d_in[1];
    const int*   src  = (const int*)d_in[2];
    const int*   dst  = (const int*)d_in[3];
    const int*   rel  = (const int*)d_in[4];
    const float* norm = (const float*)d_in[5];
    float* out = (float*)d_out;

    char* ws = (char*)d_ws;
    int*    gcnt  = (int*)(ws);
    int*    base  = (int*)(ws + 0x1000);
    int*    cur   = (int*)(ws + 0x2000);
    int*    offs  = (int*)(ws + 0x3000);
    int2*   pay   = (int2*)(ws + 0x100000);
    __bf16* Wfrag = (__bf16*)(ws + 0xD40000);
    __bf16* T     = (__bf16*)(ws + 0xE00000);

    // Pick the largest rel-group size whose T fits the workspace (expect G=1).
    const size_t tbytes_full = (size_t)N_NODES * N_REL * D * sizeof(__bf16); // 204.8 MB
    int G = 1;
    while (G < N_REL) {
        if ((size_t)0xE00000 + tbytes_full / G <= ws_size) break;
        G <<= 1;
    }
    const int rpg = N_REL / G;

    k_zeroc<<<1, 512, 0, stream>>>(gcnt);
    k_hist2<<<SC_BLOCKS, 256, 0, stream>>>(dst, gcnt);
    k_scanc<<<1, 512, 0, stream>>>(gcnt, base, cur);
    k_scatter2<<<SC_BLOCKS, 256, 0, stream>>>(src, dst, rel, norm, cur, pay);
    k_sort<<<NB, 512, 0, stream>>>(base, pay, offs);
    k_wconv<<<N_REL, 256, 0, stream>>>(W, Wfrag);

    for (int g = 0; g < G; ++g) {
        k_pre<<<PRE_BLOCKS, 256, 0, stream>>>(h, Wfrag, T, g * rpg, rpg);
        k_out<<<N_NODES / 4, 256, 0, stream>>>((const unsigned short*)T, offs, pay, out,
                                               g * rpg, (g + 1) * rpg, rpg, g == 0);
    }
}

// Round 7
// 275.679 us; speedup vs baseline: 3.3503x; 1.0543x over previous
//
#include <hip/hip_runtime.h>

// R-GCN layer: out[v] = sum_{e: dst[e]=v} norm[e] * (h[src[e]] @ W[rel[e]])
//
// v7: k_pre store-stream fixes. (1) T transposed to [rl][node][64] so each
// MFMA fragment store's 16 rows land in one contiguous 2KB window (full-line
// L2 merging) instead of 16 rows 4KB apart. (2) rels split across grid.y=4
// (3128 blocks) so the write stream has 4x the waves to drain behind.
// Payload key becomes rel*N_NODES+src (<2^21, dl<<21 packing unchanged).
// k_out unrolled 8-wide for deeper gather MLP.
//   k_hist2    coarse histogram (391 buckets of 128 nodes)
//   k_scanc    scan of 391 bucket counts
//   k_scatter2 per-block LDS counting sort of 8192 edges -> burst writes
//   k_sort     per-bucket exact sort by dst + offs[]
//   k_wconv    pack W -> per-lane bf16 MFMA fragments
//   k_pre      T[rl][n][:] = bf16(h[n] @ W[r]), h staged once per chunk
//   k_out      one wave per dst node, 8-wide unrolled gather-FMA, plain store

#define N_NODES 50000
#define N_EDGES 1600000
#define D 64
#define N_REL 32

#define BSHIFT 7                 // 128 nodes per coarse bucket
#define NPB 128
#define NB 391                   // ceil(50000/128)
#define EPB 8192                 // edges per scatter/hist block
#define SC_BLOCKS 196            // ceil(1.6M/8192)
#define SORT_CAP 8192            // bucket capacity (mean 4096, sd 64)

#define PRE_CHUNK 64
#define PRE_BLOCKS 782           // ceil(50000/64)
#define RELS_PER_BLOCK 8

typedef __attribute__((ext_vector_type(8))) __bf16 bf16x8;
typedef __attribute__((ext_vector_type(4))) __bf16 bf16x4;
typedef __attribute__((ext_vector_type(4))) float f32x4;

// ws layout (bytes):
//   [0x0000, 0x1000)      gcnt[NB] ints
//   [0x1000, 0x2000)      base[NB+1] ints
//   [0x2000, 0x3000)      cursor[NB] ints
//   [0x3000, 0x35000)     offs[50001] ints
//   [0x100000, 0xD40000)  payload int2[1.6M] (12.8 MB)
//   [0xD40000, 0xD80000)  Wfrag bf16 [32][2][4][64][8]  (256 KB)
//   [0xE00000, ...)       T bf16 [rpg][N_NODES][64]  (204.8 MB / G)

__global__ __launch_bounds__(512) void k_zeroc(int* __restrict__ gcnt) {
    if (threadIdx.x < NB) gcnt[threadIdx.x] = 0;
}

__global__ __launch_bounds__(256) void k_hist2(const int* __restrict__ dst,
                                               int* __restrict__ gcnt) {
    __shared__ int lc[NB];
    for (int b = threadIdx.x; b < NB; b += 256) lc[b] = 0;
    __syncthreads();
    const int e0 = blockIdx.x * EPB;
    #pragma unroll
    for (int j = 0; j < 32; ++j) {
        int e = e0 + j * 256 + threadIdx.x;
        if (e < N_EDGES) atomicAdd(&lc[dst[e] >> BSHIFT], 1);
    }
    __syncthreads();
    for (int b = threadIdx.x; b < NB; b += 256)
        if (lc[b]) atomicAdd(&gcnt[b], lc[b]);
}

// Exclusive scan of gcnt[0..NB) -> base[0..NB], base[NB]=total; cursor=base.
__global__ __launch_bounds__(512) void k_scanc(const int* __restrict__ gcnt,
                                               int* __restrict__ base,
                                               int* __restrict__ cur) {
    const int t = threadIdx.x;
    const int lane = t & 63;
    const int w = t >> 6;
    int v = (t < NB) ? gcnt[t] : 0;
    int x = v;
    #pragma unroll
    for (int d = 1; d < 64; d <<= 1) {
        int n = __shfl_up(x, d, 64);
        if (lane >= d) x += n;
    }
    __shared__ int wt[8];
    if (lane == 63) wt[w] = x;
    __syncthreads();
    if (t == 0) {
        int run = 0;
        #pragma unroll
        for (int i = 0; i < 8; ++i) { int tmp = wt[i]; wt[i] = run; run += tmp; }
    }
    __syncthreads();
    int excl = x - v + wt[w];
    if (t < NB) { base[t] = excl; cur[t] = excl; }
    if (t == NB - 1) base[NB] = excl + v;
}

// Per-block LDS counting sort of 8192 edges into NB coarse buckets, then
// burst-write contiguous per-bucket runs to globally reserved ranges.
// payload: x = (dstLocal<<21) | (rel*N_NODES + src), y = bits(norm)
__global__ __launch_bounds__(256) void k_scatter2(
        const int* __restrict__ src, const int* __restrict__ dst,
        const int* __restrict__ rel, const float* __restrict__ norm,
        int* __restrict__ cur, int2* __restrict__ pay) {
    __shared__ int cnt[NB];
    __shared__ int bl[NB + 1];
    __shared__ int gb[NB];
    __shared__ unsigned short bid[EPB];
    __shared__ int2 stage[EPB];
    __shared__ int wt[8];

    const int t = threadIdx.x;
    const int lane = t & 63;
    const int w = t >> 6;
    const int e0 = blockIdx.x * EPB;

    for (int b = t; b < NB; b += 256) cnt[b] = 0;
    __syncthreads();

    // pass 1: count
    #pragma unroll
    for (int j = 0; j < 32; ++j) {
        int e = e0 + j * 256 + t;
        if (e < N_EDGES) atomicAdd(&cnt[dst[e] >> BSHIFT], 1);
    }
    __syncthreads();

    // exclusive scan of cnt[0..NB)
    {
        int x0 = (t < NB) ? cnt[t] : 0;
        int x1 = (t + 256 < NB) ? cnt[t + 256] : 0;
        int s0 = x0, s1 = x1;
        #pragma unroll
        for (int d = 1; d < 64; d <<= 1) {
            int n0 = __shfl_up(s0, d, 64);
            int n1 = __shfl_up(s1, d, 64);
            if (lane >= d) { s0 += n0; s1 += n1; }
        }
        if (lane == 63) { wt[w] = s0; wt[4 + w] = s1; }
        __syncthreads();
        if (t == 0) {
            int run = 0;
            #pragma unroll
            for (int i = 0; i < 8; ++i) { int tmp = wt[i]; wt[i] = run; run += tmp; }
        }
        __syncthreads();
        int ex0 = s0 - x0 + wt[w];
        int ex1 = s1 - x1 + wt[4 + w];
        if (t < NB) bl[t] = ex0;
        if (t + 256 < NB) bl[t + 256] = ex1;
        if (t == 0) {
            int tot = e0 + EPB <= N_EDGES ? EPB : (N_EDGES > e0 ? N_EDGES - e0 : 0);
            bl[NB] = tot;
        }
    }
    __syncthreads();

    // reserve global ranges (one atomic per non-empty bucket per block)
    for (int b = t; b < NB; b += 256) {
        int c = bl[b + 1] - bl[b];
        gb[b] = c ? atomicAdd(&cur[b], c) : 0;
    }
    for (int b = t; b < NB; b += 256) cnt[b] = 0;
    __syncthreads();

    // pass 2: stage into LDS in bucket-grouped order
    #pragma unroll
    for (int j = 0; j < 32; ++j) {
        int e = e0 + j * 256 + t;
        if (e < N_EDGES) {
            int dv = dst[e];
            int b = dv >> BSHIFT;
            int r = atomicAdd(&cnt[b], 1);
            int pos = bl[b] + r;
            stage[pos] = make_int2(((dv & (NPB - 1)) << 21) | (rel[e] * N_NODES + src[e]),
                                   __float_as_int(norm[e]));
            bid[pos] = (unsigned short)b;
        }
    }
    __syncthreads();

    // pass 3: burst write to global reserved ranges (coalesced runs)
    const int total = bl[NB];
    for (int p = t; p < total; p += 256) {
        int b = bid[p];
        pay[gb[b] + (p - bl[b])] = stage[p];
    }
}

// One block per coarse bucket: stage the bucket's edges in LDS, counting-sort
// by exact local dst, write back IN PLACE in sorted order, and emit per-node
// global offsets (bucket base + local exclusive scan).
__global__ __launch_bounds__(512) void k_sort(
        const int* __restrict__ base, int2* __restrict__ pay,
        int* __restrict__ offs) {
    __shared__ int2 stage[SORT_CAP];   // 64 KB
    __shared__ int cnt[NPB];
    __shared__ int curl[NPB];
    __shared__ int wsum[2];

    const int t = threadIdx.x;
    const int lane = t & 63;
    const int b = blockIdx.x;
    const int s = base[b];
    const int e = base[b + 1];
    const int n = min(e - s, SORT_CAP);   // clamp: overflow degrades, never faults

    if (t < NPB) cnt[t] = 0;
    __syncthreads();

    // stage + count
    for (int j = t; j < n; j += 512) {
        int2 p = pay[s + j];
        stage[j] = p;
        atomicAdd(&cnt[p.x >> 21], 1);
    }
    __syncthreads();

    // exclusive scan of cnt[0..128) with 2 waves
    int vcnt = 0, x = 0;
    if (t < NPB) {
        vcnt = cnt[t];
        x = vcnt;
        #pragma unroll
        for (int d = 1; d < 64; d <<= 1) {
            int nn = __shfl_up(x, d, 64);
            if (lane >= d) x += nn;
        }
        if (lane == 63) wsum[t >> 6] = x;
    }
    __syncthreads();
    if (t < NPB) {
        int excl = x - vcnt + ((t >= 64) ? wsum[0] : 0);
        curl[t] = excl;
        int node = b * NPB + t;
        if (node < N_NODES) offs[node] = s + excl;
    }
    if (b == NB - 1 && t == 0) offs[N_NODES] = e;
    __syncthreads();

    // scatter back in place, sorted by local dst
    for (int j = t; j < n; j += 512) {
        int2 p = stage[j];
        int pos = atomicAdd(&curl[p.x >> 21], 1);
        pay[s + pos] = p;
    }
}

// Pack W into per-lane MFMA A-fragment order:
// Wfrag[r][kt][ot][lane][j] = bf16( W[r][kt*32 + (lane>>4)*8 + j][ot*16 + (lane&15)] )
__global__ __launch_bounds__(256) void k_wconv(const float* __restrict__ W,
                                               __bf16* __restrict__ Wfrag) {
    const int r = blockIdx.x;
    const int lane = threadIdx.x & 63;
    const int jj = (threadIdx.x >> 6) * 2;   // 2 elems per thread per frag
    const int q = lane >> 4;
    const int m = lane & 15;
    const float* Wr = W + (size_t)r * D * D;
    #pragma unroll
    for (int kt = 0; kt < 2; ++kt) {
        #pragma unroll
        for (int ot = 0; ot < 4; ++ot) {
            size_t dbase = ((((size_t)r * 2 + kt) * 4 + ot) * 64 + lane) * 8 + jj;
            Wfrag[dbase]     = (__bf16)Wr[(kt * 32 + q * 8 + jj) * D + ot * 16 + m];
            Wfrag[dbase + 1] = (__bf16)Wr[(kt * 32 + q * 8 + jj + 1) * D + ot * 16 + m];
        }
    }
}

// T[rl][n][:] = h[n] @ W[r0+rl], bf16.  One block per (64-node chunk, 8-rel
// group); h staged once in LDS (bf16, XOR-swizzled 16B chunks); waves loop
// over the block's rels, reading W from packed Wfrag. T is rel-major so each
// fragment store's 16 node-rows fall in one contiguous 2KB window.
__global__ __launch_bounds__(256) void k_pre(
        const float* __restrict__ h, const __bf16* __restrict__ Wfrag,
        __bf16* __restrict__ T, int r0, int rpg) {
    __shared__ unsigned short hl[PRE_CHUNK * D];   // 8 KB
    const int t = threadIdx.x;
    const int lane = t & 63;
    const int w = t >> 6;
    const int m = lane & 15;
    const int q = lane >> 4;
    const int chunk0 = blockIdx.x * PRE_CHUNK;
    const int rlb = blockIdx.y * RELS_PER_BLOCK;
    const int rle = min(rlb + RELS_PER_BLOCK, rpg);

    // stage h[chunk0 .. chunk0+64) as bf16, swizzled
    #pragma unroll
    for (int it = 0; it < 4; ++it) {
        int F = it * 256 + t;                  // float4 index over 64x64 floats
        int row = F >> 4;
        int gnode = min(chunk0 + row, N_NODES - 1);
        float4 v = ((const float4*)(h + (size_t)gnode * D))[F & 15];
        int c = (F & 15) >> 1;
        int off4 = (F & 1) * 4;
        bf16x4 o;
        o[0] = (__bf16)v.x; o[1] = (__bf16)v.y; o[2] = (__bf16)v.z; o[3] = (__bf16)v.w;
        *(bf16x4*)(hl + row * D + ((c ^ (row & 7)) << 3) + off4) = o;
    }
    __syncthreads();

    const f32x4 vzero = {0.f, 0.f, 0.f, 0.f};
    for (int rl = rlb + w; rl < rle; rl += 4) {
        const int r = r0 + rl;
        // load packed W fragments: 8 coalesced 16B loads
        bf16x8 wf[2][4];
        #pragma unroll
        for (int kt = 0; kt < 2; ++kt)
            #pragma unroll
            for (int ot = 0; ot < 4; ++ot)
                wf[kt][ot] = *(const bf16x8*)(Wfrag + ((((size_t)r * 2 + kt) * 4 + ot) * 64 + lane) * 8);

        __bf16* tplane = T + (size_t)rl * N_NODES * D;
        #pragma unroll
        for (int nt = 0; nt < 4; ++nt) {
            const int ln = nt * 16 + m;
            bf16x8 a0 = *(const bf16x8*)(hl + ln * D + (((0 * 4 + q) ^ (ln & 7)) << 3));
            bf16x8 a1 = *(const bf16x8*)(hl + ln * D + (((1 * 4 + q) ^ (ln & 7)) << 3));
            f32x4 acc[4];
            #pragma unroll
            for (int ot = 0; ot < 4; ++ot) acc[ot] = vzero;
            #pragma unroll
            for (int ot = 0; ot < 4; ++ot) {
                acc[ot] = __builtin_amdgcn_mfma_f32_16x16x32_bf16(wf[0][ot], a0, acc[ot], 0, 0, 0);
                acc[ot] = __builtin_amdgcn_mfma_f32_16x16x32_bf16(wf[1][ot], a1, acc[ot], 0, 0, 0);
            }
            const int node = chunk0 + ln;
            if (node < N_NODES) {
                __bf16* trow = tplane + (size_t)node * D;
                #pragma unroll
                for (int ot = 0; ot < 4; ++ot) {
                    bf16x4 o;
                    o[0] = (__bf16)acc[ot][0];
                    o[1] = (__bf16)acc[ot][1];
                    o[2] = (__bf16)acc[ot][2];
                    o[3] = (__bf16)acc[ot][3];
                    *(bf16x4*)(trow + ot * 16 + q * 4) = o;
                }
            }
        }
    }
}

// One wave per dst node; lane = out dim. Per edge: uniform 8B payload load +
// one coalesced 128B line gather from T + FMA. Plain store, no atomics.
// 8-wide unroll: 8 independent gathers in flight per wave.
__global__ __launch_bounds__(256) void k_out(
        const unsigned short* __restrict__ T, const int* __restrict__ offs,
        const int2* __restrict__ pay, float* __restrict__ out,
        int r0, int r1, int rpg, int first) {
    const int v = (blockIdx.x << 2) + (threadIdx.x >> 6);
    const int lane = threadIdx.x & 63;
    const int s = offs[v];
    const int e = offs[v + 1];
    const size_t orow = ((size_t)v << 6) + lane;

    float acc0 = first ? 0.f : out[orow];
    float acc1 = 0.f, acc2 = 0.f, acc3 = 0.f;
    int i = s;
    if (rpg == N_REL) {
        for (; i + 8 <= e; i += 8) {
            int2 p[8];
            #pragma unroll
            for (int u = 0; u < 8; ++u) p[u] = pay[i + u];
            float tv[8];
            #pragma unroll
            for (int u = 0; u < 8; ++u)
                tv[u] = __uint_as_float(((unsigned int)T[((size_t)(p[u].x & 0x1FFFFF) << 6) + lane]) << 16);
            acc0 = fmaf(__int_as_float(p[0].y), tv[0], acc0);
            acc1 = fmaf(__int_as_float(p[1].y), tv[1], acc1);
            acc2 = fmaf(__int_as_float(p[2].y), tv[2], acc2);
            acc3 = fmaf(__int_as_float(p[3].y), tv[3], acc3);
            acc0 = fmaf(__int_as_float(p[4].y), tv[4], acc0);
            acc1 = fmaf(__int_as_float(p[5].y), tv[5], acc1);
            acc2 = fmaf(__int_as_float(p[6].y), tv[6], acc2);
            acc3 = fmaf(__int_as_float(p[7].y), tv[7], acc3);
        }
        for (; i < e; ++i) {
            int2 p = pay[i];
            float tv = __uint_as_float(((unsigned int)T[((size_t)(p.x & 0x1FFFFF) << 6) + lane]) << 16);
            acc0 = fmaf(__int_as_float(p.y), tv, acc0);
        }
    } else {
        // grouped fallback (small workspace): only rels in [r0, r1)
        for (; i < e; ++i) {
            int2 p = pay[i];
            int key = p.x & 0x1FFFFF;
            int rlv = key / N_NODES;
            if (rlv >= r0 && rlv < r1) {
                size_t row = (size_t)(rlv - r0) * N_NODES + (key - rlv * N_NODES);
                float tv = __uint_as_float(((unsigned int)T[(row << 6) + lane]) << 16);
                acc0 = fmaf(__int_as_float(p.y), tv, acc0);
            }
        }
    }
    out[orow] = (acc0 + acc1) + (acc2 + acc3);
}

extern "C" void kernel_launch(void* const* d_in, const int* in_sizes, int n_in,
                              void* d_out, int out_size, void* d_ws, size_t ws_size,
                              hipStream_t stream) {
    const float* h    = (const float*)d_in[0];
    const float* W    = (const float*)d_in[1];
    const int*   src  = (const int*)d_in[2];
    const int*   dst  = (const int*)d_in[3];
    const int*   rel  = (const int*)d_in[4];
    const float* norm = (const float*)d_in[5];
    float* out = (float*)d_out;

    char* ws = (char*)d_ws;
    int*    gcnt  = (int*)(ws);
    int*    base  = (int*)(ws + 0x1000);
    int*    cur   = (int*)(ws + 0x2000);
    int*    offs  = (int*)(ws + 0x3000);
    int2*   pay   = (int2*)(ws + 0x100000);
    __bf16* Wfrag = (__bf16*)(ws + 0xD40000);
    __bf16* T     = (__bf16*)(ws + 0xE00000);

    // Pick the largest rel-group size whose T fits the workspace (expect G=1).
    const size_t tbytes_full = (size_t)N_NODES * N_REL * D * sizeof(__bf16); // 204.8 MB
    int G = 1;
    while (G < N_REL) {
        if ((size_t)0xE00000 + tbytes_full / G <= ws_size) break;
        G <<= 1;
    }
    const int rpg = N_REL / G;

    k_zeroc<<<1, 512, 0, stream>>>(gcnt);
    k_hist2<<<SC_BLOCKS, 256, 0, stream>>>(dst, gcnt);
    k_scanc<<<1, 512, 0, stream>>>(gcnt, base, cur);
    k_scatter2<<<SC_BLOCKS, 256, 0, stream>>>(src, dst, rel, norm, cur, pay);
    k_sort<<<NB, 512, 0, stream>>>(base, pay, offs);
    k_wconv<<<N_REL, 256, 0, stream>>>(W, Wfrag);

    for (int g = 0; g < G; ++g) {
        dim3 pgrid(PRE_BLOCKS, (rpg + RELS_PER_BLOCK - 1) / RELS_PER_BLOCK);
        k_pre<<<pgrid, 256, 0, stream>>>(h, Wfrag, T, g * rpg, rpg);
        k_out<<<N_NODES / 4, 256, 0, stream>>>((const unsigned short*)T, offs, pay, out,
                                               g * rpg, (g + 1) * rpg, rpg, g == 0);
    }
}